// Round 15
// baseline (1891.586 us; speedup 1.0000x reference)
//
#include <hip/hip_runtime.h>
#include <hip/hip_bf16.h>
#include <math.h>

// GPT-2 small forward: L=12, T=1024, D=1024, H=16, HD=64, V=50257, B=1
#define Lnum 12
#define Tn 1024
#define Dm 1024
#define Hn 16
#define HDn 64
#define Vn 50257

typedef __bf16 bf16;
typedef __bf16 bf16x4 __attribute__((ext_vector_type(4)));
typedef __bf16 bf16x8 __attribute__((ext_vector_type(8)));
typedef float f32x4 __attribute__((ext_vector_type(4)));

__device__ __forceinline__ void gload_lds16(const void* g, void* l) {
    __builtin_amdgcn_global_load_lds(
        (const __attribute__((address_space(1))) void*)g,
        (__attribute__((address_space(3))) void*)l, 16, 0, 0);
}

template <int N> __device__ __forceinline__ void vm_wait() {
    if constexpr (N == 0)      asm volatile("s_waitcnt vmcnt(0)" ::: "memory");
    else if constexpr (N == 8) asm volatile("s_waitcnt vmcnt(8)" ::: "memory");
}

__device__ __forceinline__ float gelu_f(float x) {
    const float c = 0.7978845608028654f; // sqrt(2/pi)
    return 0.5f * x * (1.0f + tanhf(c * (x + 0.044715f * x * x * x)));
}

// ---------------- embedding (float4) ----------------
__global__ __launch_bounds__(256) void embed_k(const int* __restrict__ x,
                                               const float* __restrict__ tok,
                                               const float* __restrict__ pos,
                                               float* __restrict__ h) {
    int t = blockIdx.x;
    int id = x[t];
    const float4* tr = (const float4*)(tok + (size_t)id * Dm);
    const float4* pr = (const float4*)(pos + (size_t)t * Dm);
    float4* hr = (float4*)(h + (size_t)t * Dm);
    int i = threadIdx.x;
    float4 a = tr[i], b = pr[i];
    hr[i] = make_float4(a.x + b.x, a.y + b.y, a.z + b.z, a.w + b.w);
}

// ---------------- shared bodies ----------------
__device__ __forceinline__ void ln_body(const float* __restrict__ x,
                                        const float* __restrict__ g,
                                        const float* __restrict__ b,
                                        bf16* __restrict__ y, int row,
                                        float* rs, float* rs2) {
    int tid = threadIdx.x;
    const float* xr = x + (size_t)row * Dm;
    float4 v = ((const float4*)xr)[tid];
    float s = v.x + v.y + v.z + v.w;
    float s2 = v.x * v.x + v.y * v.y + v.z * v.z + v.w * v.w;
    rs[tid] = s; rs2[tid] = s2;
    __syncthreads();
    for (int off = 128; off; off >>= 1) {
        if (tid < off) { rs[tid] += rs[tid + off]; rs2[tid] += rs2[tid + off]; }
        __syncthreads();
    }
    float mean = rs[0] * (1.0f / Dm);
    float var = rs2[0] * (1.0f / Dm) - mean * mean;
    float inv = rsqrtf(var + 1e-5f);
    float4 gg = ((const float4*)g)[tid];
    float4 bb = ((const float4*)b)[tid];
    bf16x4 pk;
    pk[0] = (bf16)((v.x - mean) * inv * gg.x + bb.x);
    pk[1] = (bf16)((v.y - mean) * inv * gg.y + bb.y);
    pk[2] = (bf16)((v.z - mean) * inv * gg.z + bb.z);
    pk[3] = (bf16)((v.w - mean) * inv * gg.w + bb.w);
    *(bf16x4*)(y + (size_t)row * Dm + tid * 4) = pk;
}

// W (K x N fp32) tile (k0,n0) 64x64 -> WT (N x K bf16); float4 loads, bf16x8 stores.
__device__ __forceinline__ void tconv_body(const float* __restrict__ W,
                                           bf16* __restrict__ WT,
                                           int K, int N, int n0, int k0,
                                           float (*t)[65]) {
    const int tid = threadIdx.x;
    {
        int ty = tid >> 4;            // 0..15
        int tx = tid & 15;            // n-quarter
#pragma unroll
        for (int r = 0; r < 4; ++r) {
            int k = r * 16 + ty;
            float4 v = *(const float4*)&W[(size_t)(k0 + k) * N + n0 + tx * 4];
            t[k][tx * 4 + 0] = v.x; t[k][tx * 4 + 1] = v.y;
            t[k][tx * 4 + 2] = v.z; t[k][tx * 4 + 3] = v.w;
        }
    }
    __syncthreads();
    {
        int nrow = tid >> 2;          // 0..63
        int ks = (tid & 3) * 16;      // k-segment
        bf16x8 p0, p1;
#pragma unroll
        for (int j = 0; j < 8; ++j) p0[j] = (bf16)t[ks + j][nrow];
#pragma unroll
        for (int j = 0; j < 8; ++j) p1[j] = (bf16)t[ks + 8 + j][nrow];
        bf16* dst = WT + (size_t)(n0 + nrow) * K + k0 + ks;
        *(bf16x8*)dst = p0;
        *(bf16x8*)(dst + 8) = p1;
    }
}

// ---------------- fused per-layer: weight tconv (3072 blocks) + LN1 (1024) ----
__global__ __launch_bounds__(256) void tconv_ln_k(const float* __restrict__ qw,
                                                  const float* __restrict__ ow,
                                                  const float* __restrict__ f1,
                                                  const float* __restrict__ f2,
                                                  bf16* __restrict__ Wl,
                                                  const float* __restrict__ h,
                                                  const float* __restrict__ lg,
                                                  const float* __restrict__ lb,
                                                  bf16* __restrict__ xn) {
    __shared__ float smem[64][65];
    int blk = blockIdx.x;
    if (blk < 3072) {
        const float* W; bf16* WT; int K, N, bi;
        if (blk < 768)       { W = qw; WT = Wl;           K = 1024; N = 3072; bi = blk; }
        else if (blk < 1024) { W = ow; WT = Wl + 3145728; K = 1024; N = 1024; bi = blk - 768; }
        else if (blk < 2048) { W = f1; WT = Wl + 4194304; K = 1024; N = 4096; bi = blk - 1024; }
        else                 { W = f2; WT = Wl + 8388608; K = 4096; N = 1024; bi = blk - 2048; }
        int nx = N >> 6;
        tconv_body(W, WT, K, N, (bi % nx) * 64, (bi / nx) * 64, smem);
    } else {
        ln_body(h, lg, lb, xn, blk - 3072, &smem[0][0], &smem[8][0]);
    }
}

// standalone LN (used for ln2 and the non-big_ws final LN)
__global__ __launch_bounds__(256) void ln_k(const float* __restrict__ x,
                                            const float* __restrict__ g,
                                            const float* __restrict__ b,
                                            bf16* __restrict__ y) {
    __shared__ float rs[256], rs2[256];
    ln_body(x, g, b, y, blockIdx.x, rs, rs2);
}

// ---------------- fused final LN (1024 blocks) + lm_w fp32->bf16 (2048) -----
__global__ __launch_bounds__(256) void lnf_cvt_k(const float* __restrict__ h,
                                                 const float* __restrict__ lg,
                                                 const float* __restrict__ lb,
                                                 bf16* __restrict__ xn,
                                                 const float* __restrict__ lw,
                                                 bf16* __restrict__ lw_bf, int n8) {
    int blk = blockIdx.x;
    if (blk < 1024) {
        __shared__ float rs[256], rs2[256];
        ln_body(h, lg, lb, xn, blk, rs, rs2);
    } else {
        int tid = threadIdx.x;
        for (int i = (blk - 1024) * 256 + tid; i < n8; i += 2048 * 256) {
            float4 f0 = ((const float4*)lw)[i * 2];
            float4 f1 = ((const float4*)lw)[i * 2 + 1];
            bf16x8 pk;
            pk[0] = (bf16)f0.x; pk[1] = (bf16)f0.y; pk[2] = (bf16)f0.z; pk[3] = (bf16)f0.w;
            pk[4] = (bf16)f1.x; pk[5] = (bf16)f1.y; pk[6] = (bf16)f1.z; pk[7] = (bf16)f1.w;
            *(bf16x8*)(lw_bf + (size_t)i * 8) = pk;
        }
    }
}

// ---------------- 4-wave MFMA GEMM ----------------
// BK=64, rows 128B, XOR-swizzled (byte ^= (row&7)<<4), linear LDS dest +
// pre-swizzled global src for gload_lds. Staging pointers hoisted.
// DBUF=0: classic 2-barrier (__syncthreads) loop.
// DBUF=1 (BMODE 0 only): double-buffered with RAW s_barrier + counted vmcnt(8)
//   so next-tile loads stay in flight across barriers (T4; __syncthreads would
//   drain vmcnt(0) and nullify the pipeline -- R10 lesson).
//   Safety: vm_wait<8> before barrier-1 = this wave's current-tile slice landed
//   (8 newest outstanding = next tile); barrier-1 publishes all slices; every
//   ds_read is consumed by an MFMA before barrier-2 (lgkm drained by issue
//   order); barrier-2 protects buffer reuse. Uniform trip count across waves.
// BMODE 0: bf16 B; BMODE 1: fp32 B reg-stage fallback.
// 1D grid, XCD-grouped decode (nbn % 8 == 0).
template <int BM, int BN, int ACT, bool RESID, bool OUTBF, int BMODE, bool NTAIL, bool DBUF>
__global__ __launch_bounds__(256) void mgemm_k(const bf16* __restrict__ A,
                                               const void* __restrict__ Btv,
                                               const float* __restrict__ bias,
                                               const float* __restrict__ resid,
                                               void* __restrict__ Cv,
                                               int N, int K, int nbm, int nbn) {
    constexpr int MI = BM / 32;
    constexpr int NJ = BN / 32;
    constexpr int NBUF = DBUF ? 2 : 1;
    __shared__ bf16 As[NBUF * BM * 64];
    __shared__ bf16 Bs[NBUF * BN * 64];
    const int tid = threadIdx.x;
    const int lane = tid & 63;
    const int wid = tid >> 6;

    const int bfl = blockIdx.x;
    const int xcd = bfl & 7;
    const int t1 = bfl >> 3;
    const int rr = t1 % nbm;
    const int cg = t1 / nbm;
    const int bm = rr * BM;
    const int bn = (cg * 8 + xcd) * BN;

    const int wr = (wid >> 1) * (BM / 2);
    const int wc = (wid & 1) * (BN / 2);
    const int l15 = lane & 15;
    const int l4 = lane >> 4;

    f32x4 acc[MI][NJ] = {};

    // ---- hoisted per-thread staging source pointers ----
    const bf16* aSrc[MI * 2];
#pragma unroll
    for (int u = 0; u < BM / 32; ++u) {
        int ch = u * 256 + tid;
        int row = ch >> 3;
        int cb = (ch & 7) * 16;
        int ksw = (cb ^ ((row & 7) << 4)) >> 1;
        aSrc[u] = A + (size_t)(bm + row) * K + ksw;
    }
    const bf16* bSrc[NJ * 2];
    if (BMODE == 0) {
        const bf16* B = (const bf16*)Btv;
#pragma unroll
        for (int u = 0; u < BN / 32; ++u) {
            int ch = u * 256 + tid;
            int row = ch >> 3;
            int cb = (ch & 7) * 16;
            int ksw = (cb ^ ((row & 7) << 4)) >> 1;
            bSrc[u] = B + (size_t)(bn + row) * K + ksw;
        }
    }

    auto stage = [&](int half, int k0) {
#pragma unroll
        for (int u = 0; u < BM / 32; ++u)
            gload_lds16(aSrc[u] + k0, &As[half * BM * 64 + u * 2048 + wid * 512]);
#pragma unroll
        for (int u = 0; u < BN / 32; ++u)
            gload_lds16(bSrc[u] + k0, &Bs[half * BN * 64 + u * 2048 + wid * 512]);
    };

    auto compute = [&](int half) {
        const char* aB = (const char*)&As[half * BM * 64];
        const char* bB = (const char*)&Bs[half * BN * 64];
#pragma unroll
        for (int kk = 0; kk < 2; ++kk) {
            const int kb = kk * 64 + l4 * 16;
            bf16x8 a[MI], b[NJ];
#pragma unroll
            for (int i = 0; i < MI; ++i) {
                int row = wr + i * 16 + l15;
                a[i] = *(const bf16x8*)(aB + row * 128 + (kb ^ ((row & 7) << 4)));
            }
#pragma unroll
            for (int j = 0; j < NJ; ++j) {
                int row = wc + j * 16 + l15;
                b[j] = *(const bf16x8*)(bB + row * 128 + (kb ^ ((row & 7) << 4)));
            }
#pragma unroll
            for (int i = 0; i < MI; ++i)
#pragma unroll
                for (int j = 0; j < NJ; ++j)
                    acc[i][j] = __builtin_amdgcn_mfma_f32_16x16x32_bf16(a[i], b[j], acc[i][j], 0, 0, 0);
        }
    };

    if constexpr (DBUF) {
        static_assert(BMODE == 0, "DBUF requires bf16 B");
        const int nt = K >> 6;
        stage(0, 0);
        int cur = 0;
        for (int t = 0; t < nt; ++t) {
            if (t + 1 < nt) {
                stage(cur ^ 1, (t + 1) << 6);   // next-tile loads in flight
                vm_wait<8>();                   // current tile's 8 loads landed
            } else {
                vm_wait<0>();
            }
            asm volatile("s_barrier" ::: "memory");   // raw: no vmcnt drain
            compute(cur);
            asm volatile("s_barrier" ::: "memory");   // buf[cur] free for reuse
            cur ^= 1;
        }
    } else {
        for (int k0 = 0; k0 < K; k0 += 64) {
            if (BMODE == 0) {
                stage(0, k0);
            } else {
                const float* B = (const float*)Btv;
#pragma unroll
                for (int u = 0; u < BM / 32; ++u)
                    gload_lds16(aSrc[u] + k0, &As[u * 2048 + wid * 512]);
#pragma unroll
                for (int it = 0; it < BN / 32; ++it) {
                    int gi = it * 256 + tid;
                    int row = gi >> 3;
                    int cb = (gi & 7) * 16;
                    int n = bn + row;
                    if (NTAIL && n >= N) n = N - 1;
                    const float* g = B + (size_t)n * K + k0 + (gi & 7) * 8;
                    float4 f0 = *(const float4*)g;
                    float4 f1 = *(const float4*)(g + 4);
                    bf16x8 pk;
                    pk[0] = (bf16)f0.x; pk[1] = (bf16)f0.y; pk[2] = (bf16)f0.z; pk[3] = (bf16)f0.w;
                    pk[4] = (bf16)f1.x; pk[5] = (bf16)f1.y; pk[6] = (bf16)f1.z; pk[7] = (bf16)f1.w;
                    *(bf16x8*)((char*)Bs + row * 128 + (cb ^ ((row & 7) << 4))) = pk;
                }
            }
            __syncthreads();
            compute(0);
            __syncthreads();
        }
    }

#pragma unroll
    for (int i = 0; i < MI; ++i) {
        int row0 = bm + wr + i * 16 + l4 * 4;
#pragma unroll
        for (int j = 0; j < NJ; ++j) {
            int col = bn + wc + j * 16 + l15;
            if (NTAIL && col >= N) continue;
            float bv = bias ? bias[col] : 0.f;
#pragma unroll
            for (int r = 0; r < 4; ++r) {
                float v = acc[i][j][r] + bv;
                if (ACT == 1) v = gelu_f(v);
                size_t idx = (size_t)(row0 + r) * N + col;
                if (RESID) v += resid[idx];
                if (OUTBF) ((bf16*)Cv)[idx] = (bf16)v;
                else       ((float*)Cv)[idx] = v;
            }
        }
    }
}

// ---------------- MFMA flash attention ----------------
// QBLK=32, 128 threads = 2 waves (16 q-rows each), KVBLK=64.
// 1D grid of 512 blocks (2/CU), LPT pairing balances causal load.
// Swapped QK^T (S^T = K.Q^T) so softmax per q is lane-local + 2 shuffles.
__global__ __launch_bounds__(128) void fattn_k(const bf16* __restrict__ qkv,
                                               const float* __restrict__ amask,
                                               bf16* __restrict__ out) {
    __shared__ bf16 Ks[64 * 64];      // [kr][d], rows 128B, XOR-swizzled
    __shared__ bf16 Vt[64 * 64];      // [d][k], rows 128B, XOR-swizzled
    __shared__ bf16 Pw[2][16 * 64];   // per-wave P [q][k], XOR-swizzled
    __shared__ float addb[Tn];        // attention-mask additive bias
    __shared__ float bcast[2][16];    // per-wave row-stat broadcast

    const int f = blockIdx.x;
    const int hh = f & 15;
    const int s = f >> 4;                       // 0..31
    const int qt = (s < 16) ? s : 47 - s;       // LPT pairing
    const int tid = threadIdx.x;
    const int lane = tid & 63;
    const int wq = tid >> 6;                    // 0..1
    const int l15 = lane & 15;
    const int g = lane >> 4;

    const int qglob = qt * 32 + wq * 16 + l15;
    const int nkt = (qt >> 1) + 1;
    const int kmax = nkt * 64;

    for (int i = tid; i < kmax; i += 128)
        addb[i] = (1.0f - amask[i]) * -3.0e38f;

    bf16x8 qreg[2];
    {
        const bf16* qp = qkv + (size_t)qglob * (3 * Dm) + hh * HDn + g * 8;
        qreg[0] = *(const bf16x8*)qp;
        qreg[1] = *(const bf16x8*)(qp + 32);
    }

    f32x4 accO[4] = {};               // O[q=4g+r][d=16nf+l15]
    float mrun = -3.0e38f, lrun = 0.f;

    for (int kt = 0; kt < nkt; ++kt) {
        const int kb = kt * 64;
        __syncthreads();   // previous tile fully consumed
#pragma unroll
        for (int t2 = 0; t2 < 4; ++t2) {
            int c = tid + t2 * 128;
            int kr = c >> 3;
            int d8 = (c & 7) * 8;
            const bf16* gp = qkv + (size_t)(kb + kr) * (3 * Dm) + Dm + hh * HDn + d8;
            bf16x8 v = *(const bf16x8*)gp;
            *(bf16x8*)((char*)Ks + kr * 128 + ((d8 * 2) ^ ((kr & 7) << 4))) = v;
        }
#pragma unroll
        for (int t2 = 0; t2 < 4; ++t2) {
            int c = tid + t2 * 128;
            int k = c >> 3, d0 = (c & 7) * 8;
            const bf16* gp = qkv + (size_t)(kb + k) * (3 * Dm) + 2 * Dm + hh * HDn + d0;
            bf16x8 v = *(const bf16x8*)gp;
#pragma unroll
            for (int j = 0; j < 8; ++j) {
                int d = d0 + j;
                *(bf16*)((char*)Vt + d * 128 + ((2 * k) ^ ((d & 7) << 4))) = v[j];
            }
        }
        __syncthreads();

        // ---- S^T = K . Q^T ----
        f32x4 accS[4] = {};
        __builtin_amdgcn_s_setprio(1);
#pragma unroll
        for (int s2 = 0; s2 < 2; ++s2)
#pragma unroll
            for (int mf = 0; mf < 4; ++mf) {
                int kr = mf * 16 + l15;
                bf16x8 af = *(const bf16x8*)((char*)Ks + kr * 128 + ((s2 * 64 + g * 16) ^ ((kr & 7) << 4)));
                accS[mf] = __builtin_amdgcn_mfma_f32_16x16x32_bf16(af, qreg[s2], accS[mf], 0, 0, 0);
            }
        __builtin_amdgcn_s_setprio(0);

        // ---- online softmax (stats per q = l15) ----
        float p[16];
        float tmax = -3.0e38f;
#pragma unroll
        for (int mf = 0; mf < 4; ++mf)
#pragma unroll
            for (int r = 0; r < 4; ++r) {
                int k = kb + mf * 16 + g * 4 + r;
                float sv = accS[mf][r] * 0.125f + addb[k];
                if (k > qglob) sv = -3.0e38f;     // causal
                p[mf * 4 + r] = sv;
                tmax = fmaxf(tmax, sv);
            }
        tmax = fmaxf(tmax, __shfl_xor(tmax, 16, 64));
        tmax = fmaxf(tmax, __shfl_xor(tmax, 32, 64));
        float mnew = fmaxf(mrun, tmax);
        float alpha = expf(mrun - mnew);
        float psum = 0.f;
#pragma unroll
        for (int i = 0; i < 16; ++i) { float e = expf(p[i] - mnew); p[i] = e; psum += e; }
        psum += __shfl_xor(psum, 16, 64);
        psum += __shfl_xor(psum, 32, 64);
        lrun = lrun * alpha + psum;
        mrun = mnew;

        if (g == 0) bcast[wq][l15] = alpha;
        f32x4 av = *(f32x4*)&bcast[wq][g * 4];
#pragma unroll
        for (int nf = 0; nf < 4; ++nf)
#pragma unroll
            for (int r = 0; r < 4; ++r) accO[nf][r] *= av[r];

        // ---- P (bf16) -> per-wave LDS, re-read as PV A-fragments ----
        char* pw = (char*)Pw[wq];
#pragma unroll
        for (int mf = 0; mf < 4; ++mf) {
            bf16x4 pk;
            pk[0] = (bf16)p[mf * 4 + 0]; pk[1] = (bf16)p[mf * 4 + 1];
            pk[2] = (bf16)p[mf * 4 + 2]; pk[3] = (bf16)p[mf * 4 + 3];
            *(bf16x4*)(pw + l15 * 128 + ((32 * mf + 8 * g) ^ ((l15 & 7) << 4))) = pk;
        }
        bf16x8 pa[2];
#pragma unroll
        for (int s2 = 0; s2 < 2; ++s2)
            pa[s2] = *(const bf16x8*)(pw + l15 * 128 + ((s2 * 64 + g * 16) ^ ((l15 & 7) << 4)));

        // ---- O += P . V ----
        __builtin_amdgcn_s_setprio(1);
#pragma unroll
        for (int s2 = 0; s2 < 2; ++s2)
#pragma unroll
            for (int nf = 0; nf < 4; ++nf) {
                int d = nf * 16 + l15;
                bf16x8 bfg = *(const bf16x8*)((char*)Vt + d * 128 + ((s2 * 64 + g * 16) ^ ((d & 7) << 4)));
                accO[nf] = __builtin_amdgcn_mfma_f32_16x16x32_bf16(pa[s2], bfg, accO[nf], 0, 0, 0);
            }
        __builtin_amdgcn_s_setprio(0);
    }

    if (g == 0) bcast[wq][l15] = 1.0f / lrun;
    f32x4 lv = *(f32x4*)&bcast[wq][g * 4];
#pragma unroll
    for (int nf = 0; nf < 4; ++nf)
#pragma unroll
        for (int r = 0; r < 4; ++r) {
            int row = qt * 32 + wq * 16 + 4 * g + r;
            int col = hh * HDn + nf * 16 + l15;
            out[(size_t)row * Dm + col] = (bf16)(accO[nf][r] * lv[r]);
        }
}

// ---------------- launch ----------------
extern "C" void kernel_launch(void* const* d_in, const int* in_sizes, int n_in,
                              void* d_out, int out_size, void* d_ws, size_t ws_size,
                              hipStream_t stream) {
    const int*   x      = (const int*)d_in[0];
    const float* amask  = (const float*)d_in[1];
    const float* tok    = (const float*)d_in[2];
    const float* pos    = (const float*)d_in[3];
    const float* ln1_g  = (const float*)d_in[4];
    const float* ln1_b  = (const float*)d_in[5];
    const float* qkv_w  = (const float*)d_in[6];
    const float* qkv_b  = (const float*)d_in[7];
    const float* out_w  = (const float*)d_in[8];
    const float* out_b  = (const float*)d_in[9];
    const float* ln2_g  = (const float*)d_in[10];
    const float* ln2_b  = (const float*)d_in[11];
    const float* fc1_w  = (const float*)d_in[12];
    const float* fc1_b  = (const float*)d_in[13];
    const float* fc2_w  = (const float*)d_in[14];
    const float* fc2_b  = (const float*)d_in[15];
    const float* lnf_g  = (const float*)d_in[16];
    const float* lnf_b  = (const float*)d_in[17];
    const float* lm_w   = (const float*)d_in[18];

    char* ws = (char*)d_ws;
    float* h      = (float*)(ws + 0);                       // 4 MB
    bf16*  qkv_bf = (bf16*) (ws + (4u << 20));              // 6 MB
    bf16*  xn_bf  = (bf16*) (ws + (16u << 20));             // 2 MB
    bf16*  wv_bf  = (bf16*) (ws + (18u << 20));             // 2 MB
    bf16*  ff1_bf = (bf16*) (ws + (20u << 20));             // 8 MB
    bf16*  Wbuf   = (bf16*) (ws + (28u << 20));             // 24 MB (per-layer weights)
    bf16* qT  = Wbuf;
    bf16* oT  = qT  + 3145728;
    bf16* f1T = oT  + 1048576;
    bf16* f2T = f1T + 4194304;
    bf16* lm_bf = (bf16*)(ws + (52u << 20));                // 100 MB (if ws allows)
    float* outf = (float*)d_out;

    const bool big_ws = ws_size >= ((size_t)153 << 20);

    embed_k<<<Tn, 256, 0, stream>>>(x, tok, pos, h);

    for (int l = 0; l < Lnum; ++l) {
        const float* l1g = ln1_g + (size_t)l * Dm;
        const float* l1b = ln1_b + (size_t)l * Dm;
        const float* qw  = qkv_w + (size_t)l * Dm * 3 * Dm;
        const float* qb  = qkv_b + (size_t)l * 3 * Dm;
        const float* ow  = out_w + (size_t)l * Dm * Dm;
        const float* ob  = out_b + (size_t)l * Dm;
        const float* l2g = ln2_g + (size_t)l * Dm;
        const float* l2b = ln2_b + (size_t)l * Dm;
        const float* f1w = fc1_w + (size_t)l * Dm * 4 * Dm;
        const float* f1b = fc1_b + (size_t)l * 4 * Dm;
        const float* f2w = fc2_w + (size_t)l * 4 * Dm * Dm;
        const float* f2b = fc2_b + (size_t)l * Dm;

        // fused: per-layer weight convert (cache-warm) + LN1
        tconv_ln_k<<<4096, 256, 0, stream>>>(qw, ow, f1w, f2w, Wbuf, h, l1g, l1b, xn_bf);
        // qkv = xn @ qw + qb (bf16 out): 64x64 tiles, 768 blocks (3/CU)
        mgemm_k<64, 64, 0, false, true, 0, false, false><<<768, 256, 0, stream>>>(
            xn_bf, qT, qb, nullptr, qkv_bf, 3 * Dm, Dm, 16, 48);
        // flash attention: 512 blocks x 128 thr, LPT-balanced causal
        fattn_k<<<512, 128, 0, stream>>>(qkv_bf, amask, wv_bf);
        // h = h + wv @ ow + ob: 32x64 tiles, 512 blocks (2/CU)
        mgemm_k<32, 64, 0, true, false, 0, false, false><<<512, 256, 0, stream>>>(
            wv_bf, oT, ob, h, h, Dm, Dm, 32, 16);
        ln_k<<<Tn, 256, 0, stream>>>(h, l2g, l2b, xn_bf);
        // ff1 = gelu(xn @ f1w + f1b): 64x128 tiles (2x per-barrier MFMA density),
        // 16x32 = 512 blocks (2/CU)
        mgemm_k<64, 128, 1, false, true, 0, false, false><<<512, 256, 0, stream>>>(
            xn_bf, f1T, f1b, nullptr, ff1_bf, 4 * Dm, Dm, 16, 32);
        // h = h + ff1 @ f2w + f2b: 32x64 tiles, 512 blocks (2/CU)
        mgemm_k<32, 64, 0, true, false, 0, false, false><<<512, 256, 0, stream>>>(
            ff1_bf, f2T, f2b, h, h, Dm, 4 * Dm, 32, 16);
    }

    // logits = xn @ lm_w^T: 128x128 tiles, nbn padded 393 -> 400 (NTAIL)
    if (big_ws) {
        // fused final LN + lm_w convert (independent producers)
        lnf_cvt_k<<<3072, 256, 0, stream>>>(h, lnf_g, lnf_b, xn_bf, lm_w, lm_bf,
                                            (Vn * Dm) / 8);
        // raw-barrier counted-vmcnt double-buffered pipeline (T3/T4)
        mgemm_k<128, 128, 0, false, false, 0, true, true><<<8 * 400, 256, 0, stream>>>(
            xn_bf, lm_bf, nullptr, nullptr, outf, Vn, Dm, 8, 400);
    } else {
        ln_k<<<Tn, 256, 0, stream>>>(h, lnf_g, lnf_b, xn_bf);
        mgemm_k<128, 128, 0, false, false, 1, true, false><<<8 * 400, 256, 0, stream>>>(
            xn_bf, lm_w, nullptr, nullptr, outf, Vn, Dm, 8, 400);
    }
}

// Round 16
// 1818.763 us; speedup vs baseline: 1.0400x; 1.0400x over previous
//
#include <hip/hip_runtime.h>
#include <hip/hip_bf16.h>
#include <math.h>

// GPT-2 small forward: L=12, T=1024, D=1024, H=16, HD=64, V=50257, B=1
// Best configuration (R14): per-layer cache-warm tconv+LN fusion, 4-wave BK=64
// 2-barrier MFMA GEMMs (occupancy-optimal tiles), LPT-balanced flash attention,
// bf16-preconverted LM head. R9-R15 structural variants all measured worse:
// 1-wave barrier-free (-340us), dbuf counted-vmcnt (0), BK=128 (-60us),
// upfront all-layer tconv (cold weights, -90us), raw-barrier DBUF LM head
// (occupancy loss, -30us), fc1 64x128 (-40us).
#define Lnum 12
#define Tn 1024
#define Dm 1024
#define Hn 16
#define HDn 64
#define Vn 50257

typedef __bf16 bf16;
typedef __bf16 bf16x4 __attribute__((ext_vector_type(4)));
typedef __bf16 bf16x8 __attribute__((ext_vector_type(8)));
typedef float f32x4 __attribute__((ext_vector_type(4)));

__device__ __forceinline__ void gload_lds16(const void* g, void* l) {
    __builtin_amdgcn_global_load_lds(
        (const __attribute__((address_space(1))) void*)g,
        (__attribute__((address_space(3))) void*)l, 16, 0, 0);
}

__device__ __forceinline__ float gelu_f(float x) {
    const float c = 0.7978845608028654f; // sqrt(2/pi)
    return 0.5f * x * (1.0f + tanhf(c * (x + 0.044715f * x * x * x)));
}

// ---------------- embedding (float4) ----------------
__global__ __launch_bounds__(256) void embed_k(const int* __restrict__ x,
                                               const float* __restrict__ tok,
                                               const float* __restrict__ pos,
                                               float* __restrict__ h) {
    int t = blockIdx.x;
    int id = x[t];
    const float4* tr = (const float4*)(tok + (size_t)id * Dm);
    const float4* pr = (const float4*)(pos + (size_t)t * Dm);
    float4* hr = (float4*)(h + (size_t)t * Dm);
    int i = threadIdx.x;
    float4 a = tr[i], b = pr[i];
    hr[i] = make_float4(a.x + b.x, a.y + b.y, a.z + b.z, a.w + b.w);
}

// ---------------- shared bodies ----------------
__device__ __forceinline__ void ln_body(const float* __restrict__ x,
                                        const float* __restrict__ g,
                                        const float* __restrict__ b,
                                        bf16* __restrict__ y, int row,
                                        float* rs, float* rs2) {
    int tid = threadIdx.x;
    const float* xr = x + (size_t)row * Dm;
    float4 v = ((const float4*)xr)[tid];
    float s = v.x + v.y + v.z + v.w;
    float s2 = v.x * v.x + v.y * v.y + v.z * v.z + v.w * v.w;
    rs[tid] = s; rs2[tid] = s2;
    __syncthreads();
    for (int off = 128; off; off >>= 1) {
        if (tid < off) { rs[tid] += rs[tid + off]; rs2[tid] += rs2[tid + off]; }
        __syncthreads();
    }
    float mean = rs[0] * (1.0f / Dm);
    float var = rs2[0] * (1.0f / Dm) - mean * mean;
    float inv = rsqrtf(var + 1e-5f);
    float4 gg = ((const float4*)g)[tid];
    float4 bb = ((const float4*)b)[tid];
    bf16x4 pk;
    pk[0] = (bf16)((v.x - mean) * inv * gg.x + bb.x);
    pk[1] = (bf16)((v.y - mean) * inv * gg.y + bb.y);
    pk[2] = (bf16)((v.z - mean) * inv * gg.z + bb.z);
    pk[3] = (bf16)((v.w - mean) * inv * gg.w + bb.w);
    *(bf16x4*)(y + (size_t)row * Dm + tid * 4) = pk;
}

// W (K x N fp32) tile (k0,n0) 64x64 -> WT (N x K bf16); float4 loads, bf16x8 stores.
__device__ __forceinline__ void tconv_body(const float* __restrict__ W,
                                           bf16* __restrict__ WT,
                                           int K, int N, int n0, int k0,
                                           float (*t)[65]) {
    const int tid = threadIdx.x;
    {
        int ty = tid >> 4;            // 0..15
        int tx = tid & 15;            // n-quarter
#pragma unroll
        for (int r = 0; r < 4; ++r) {
            int k = r * 16 + ty;
            float4 v = *(const float4*)&W[(size_t)(k0 + k) * N + n0 + tx * 4];
            t[k][tx * 4 + 0] = v.x; t[k][tx * 4 + 1] = v.y;
            t[k][tx * 4 + 2] = v.z; t[k][tx * 4 + 3] = v.w;
        }
    }
    __syncthreads();
    {
        int nrow = tid >> 2;          // 0..63
        int ks = (tid & 3) * 16;      // k-segment
        bf16x8 p0, p1;
#pragma unroll
        for (int j = 0; j < 8; ++j) p0[j] = (bf16)t[ks + j][nrow];
#pragma unroll
        for (int j = 0; j < 8; ++j) p1[j] = (bf16)t[ks + 8 + j][nrow];
        bf16* dst = WT + (size_t)(n0 + nrow) * K + k0 + ks;
        *(bf16x8*)dst = p0;
        *(bf16x8*)(dst + 8) = p1;
    }
}

// ---------------- fused per-layer: weight tconv (3072 blocks) + LN1 (1024) ----
// tconv and ln1 are independent (tconv: weights->Wl; ln1: h->xn); fusing saves
// a dispatch and keeps this layer's weights L2/L3-hot for the GEMMs (R12/R13).
__global__ __launch_bounds__(256) void tconv_ln_k(const float* __restrict__ qw,
                                                  const float* __restrict__ ow,
                                                  const float* __restrict__ f1,
                                                  const float* __restrict__ f2,
                                                  bf16* __restrict__ Wl,
                                                  const float* __restrict__ h,
                                                  const float* __restrict__ lg,
                                                  const float* __restrict__ lb,
                                                  bf16* __restrict__ xn) {
    __shared__ float smem[64][65];
    int blk = blockIdx.x;
    if (blk < 3072) {
        const float* W; bf16* WT; int K, N, bi;
        if (blk < 768)       { W = qw; WT = Wl;           K = 1024; N = 3072; bi = blk; }
        else if (blk < 1024) { W = ow; WT = Wl + 3145728; K = 1024; N = 1024; bi = blk - 768; }
        else if (blk < 2048) { W = f1; WT = Wl + 4194304; K = 1024; N = 4096; bi = blk - 1024; }
        else                 { W = f2; WT = Wl + 8388608; K = 4096; N = 1024; bi = blk - 2048; }
        int nx = N >> 6;
        tconv_body(W, WT, K, N, (bi % nx) * 64, (bi / nx) * 64, smem);
    } else {
        ln_body(h, lg, lb, xn, blk - 3072, &smem[0][0], &smem[8][0]);
    }
}

// standalone LN (used for ln2 and the non-big_ws final LN)
__global__ __launch_bounds__(256) void ln_k(const float* __restrict__ x,
                                            const float* __restrict__ g,
                                            const float* __restrict__ b,
                                            bf16* __restrict__ y) {
    __shared__ float rs[256], rs2[256];
    ln_body(x, g, b, y, blockIdx.x, rs, rs2);
}

// ---------------- fused final LN (1024 blocks) + lm_w fp32->bf16 (2048) -----
__global__ __launch_bounds__(256) void lnf_cvt_k(const float* __restrict__ h,
                                                 const float* __restrict__ lg,
                                                 const float* __restrict__ lb,
                                                 bf16* __restrict__ xn,
                                                 const float* __restrict__ lw,
                                                 bf16* __restrict__ lw_bf, int n8) {
    int blk = blockIdx.x;
    if (blk < 1024) {
        __shared__ float rs[256], rs2[256];
        ln_body(h, lg, lb, xn, blk, rs, rs2);
    } else {
        int tid = threadIdx.x;
        for (int i = (blk - 1024) * 256 + tid; i < n8; i += 2048 * 256) {
            float4 f0 = ((const float4*)lw)[i * 2];
            float4 f1 = ((const float4*)lw)[i * 2 + 1];
            bf16x8 pk;
            pk[0] = (bf16)f0.x; pk[1] = (bf16)f0.y; pk[2] = (bf16)f0.z; pk[3] = (bf16)f0.w;
            pk[4] = (bf16)f1.x; pk[5] = (bf16)f1.y; pk[6] = (bf16)f1.z; pk[7] = (bf16)f1.w;
            *(bf16x8*)(lw_bf + (size_t)i * 8) = pk;
        }
    }
}

// ---------------- 4-wave MFMA GEMM (BK=64, 2-barrier loop) ----------------
// Rows 128B, XOR-swizzled (byte ^= (row&7)<<4), linear LDS dest + pre-swizzled
// global src for gload_lds. Staging source pointers HOISTED out of the K-loop.
// BMODE 0: bf16 B; BMODE 1: fp32 B reg-stage fallback.
// 1D grid, XCD-grouped decode (nbn % 8 == 0).
template <int BM, int BN, int ACT, bool RESID, bool OUTBF, int BMODE, bool NTAIL>
__global__ __launch_bounds__(256) void mgemm_k(const bf16* __restrict__ A,
                                               const void* __restrict__ Btv,
                                               const float* __restrict__ bias,
                                               const float* __restrict__ resid,
                                               void* __restrict__ Cv,
                                               int N, int K, int nbm, int nbn) {
    constexpr int MI = BM / 32;
    constexpr int NJ = BN / 32;
    __shared__ bf16 As[BM * 64];
    __shared__ bf16 Bs[BN * 64];
    const int tid = threadIdx.x;
    const int lane = tid & 63;
    const int wid = tid >> 6;

    const int bfl = blockIdx.x;
    const int xcd = bfl & 7;
    const int t1 = bfl >> 3;
    const int rr = t1 % nbm;
    const int cg = t1 / nbm;
    const int bm = rr * BM;
    const int bn = (cg * 8 + xcd) * BN;

    const int wr = (wid >> 1) * (BM / 2);
    const int wc = (wid & 1) * (BN / 2);
    const int l15 = lane & 15;
    const int l4 = lane >> 4;

    f32x4 acc[MI][NJ] = {};

    // ---- hoisted per-thread staging source pointers ----
    const bf16* aSrc[MI * 2];
#pragma unroll
    for (int u = 0; u < BM / 32; ++u) {
        int ch = u * 256 + tid;
        int row = ch >> 3;
        int cb = (ch & 7) * 16;
        int ksw = (cb ^ ((row & 7) << 4)) >> 1;
        aSrc[u] = A + (size_t)(bm + row) * K + ksw;
    }
    const bf16* bSrc[NJ * 2];
    if (BMODE == 0) {
        const bf16* B = (const bf16*)Btv;
#pragma unroll
        for (int u = 0; u < BN / 32; ++u) {
            int ch = u * 256 + tid;
            int row = ch >> 3;
            int cb = (ch & 7) * 16;
            int ksw = (cb ^ ((row & 7) << 4)) >> 1;
            bSrc[u] = B + (size_t)(bn + row) * K + ksw;
        }
    }

    for (int k0 = 0; k0 < K; k0 += 64) {
#pragma unroll
        for (int u = 0; u < BM / 32; ++u)
            gload_lds16(aSrc[u] + k0, &As[u * 2048 + wid * 512]);
        if (BMODE == 0) {
#pragma unroll
            for (int u = 0; u < BN / 32; ++u)
                gload_lds16(bSrc[u] + k0, &Bs[u * 2048 + wid * 512]);
        } else {
            const float* B = (const float*)Btv;
#pragma unroll
            for (int it = 0; it < BN / 32; ++it) {
                int gi = it * 256 + tid;
                int row = gi >> 3;
                int cb = (gi & 7) * 16;
                int n = bn + row;
                if (NTAIL && n >= N) n = N - 1;
                const float* g = B + (size_t)n * K + k0 + (gi & 7) * 8;
                float4 f0 = *(const float4*)g;
                float4 f1 = *(const float4*)(g + 4);
                bf16x8 pk;
                pk[0] = (bf16)f0.x; pk[1] = (bf16)f0.y; pk[2] = (bf16)f0.z; pk[3] = (bf16)f0.w;
                pk[4] = (bf16)f1.x; pk[5] = (bf16)f1.y; pk[6] = (bf16)f1.z; pk[7] = (bf16)f1.w;
                *(bf16x8*)((char*)Bs + row * 128 + (cb ^ ((row & 7) << 4))) = pk;
            }
        }
        __syncthreads();

#pragma unroll
        for (int kk = 0; kk < 2; ++kk) {
            const int kb = kk * 64 + l4 * 16;
            bf16x8 a[MI], b[NJ];
#pragma unroll
            for (int i = 0; i < MI; ++i) {
                int row = wr + i * 16 + l15;
                a[i] = *(const bf16x8*)((char*)As + row * 128 + (kb ^ ((row & 7) << 4)));
            }
#pragma unroll
            for (int j = 0; j < NJ; ++j) {
                int row = wc + j * 16 + l15;
                b[j] = *(const bf16x8*)((char*)Bs + row * 128 + (kb ^ ((row & 7) << 4)));
            }
#pragma unroll
            for (int i = 0; i < MI; ++i)
#pragma unroll
                for (int j = 0; j < NJ; ++j)
                    acc[i][j] = __builtin_amdgcn_mfma_f32_16x16x32_bf16(a[i], b[j], acc[i][j], 0, 0, 0);
        }
        __syncthreads();
    }

#pragma unroll
    for (int i = 0; i < MI; ++i) {
        int row0 = bm + wr + i * 16 + l4 * 4;
#pragma unroll
        for (int j = 0; j < NJ; ++j) {
            int col = bn + wc + j * 16 + l15;
            if (NTAIL && col >= N) continue;
            float bv = bias ? bias[col] : 0.f;
#pragma unroll
            for (int r = 0; r < 4; ++r) {
                float v = acc[i][j][r] + bv;
                if (ACT == 1) v = gelu_f(v);
                size_t idx = (size_t)(row0 + r) * N + col;
                if (RESID) v += resid[idx];
                if (OUTBF) ((bf16*)Cv)[idx] = (bf16)v;
                else       ((float*)Cv)[idx] = v;
            }
        }
    }
}

// ---------------- MFMA flash attention ----------------
// QBLK=32, 128 threads = 2 waves (16 q-rows each), KVBLK=64.
// 1D grid of 512 blocks (2/CU), LPT pairing balances causal load.
// Swapped QK^T (S^T = K.Q^T) so softmax per q is lane-local + 2 shuffles.
__global__ __launch_bounds__(128) void fattn_k(const bf16* __restrict__ qkv,
                                               const float* __restrict__ amask,
                                               bf16* __restrict__ out) {
    __shared__ bf16 Ks[64 * 64];      // [kr][d], rows 128B, XOR-swizzled
    __shared__ bf16 Vt[64 * 64];      // [d][k], rows 128B, XOR-swizzled
    __shared__ bf16 Pw[2][16 * 64];   // per-wave P [q][k], XOR-swizzled
    __shared__ float addb[Tn];        // attention-mask additive bias
    __shared__ float bcast[2][16];    // per-wave row-stat broadcast

    const int f = blockIdx.x;
    const int hh = f & 15;
    const int s = f >> 4;                       // 0..31
    const int qt = (s < 16) ? s : 47 - s;       // LPT pairing
    const int tid = threadIdx.x;
    const int lane = tid & 63;
    const int wq = tid >> 6;                    // 0..1
    const int l15 = lane & 15;
    const int g = lane >> 4;

    const int qglob = qt * 32 + wq * 16 + l15;
    const int nkt = (qt >> 1) + 1;
    const int kmax = nkt * 64;

    for (int i = tid; i < kmax; i += 128)
        addb[i] = (1.0f - amask[i]) * -3.0e38f;

    bf16x8 qreg[2];
    {
        const bf16* qp = qkv + (size_t)qglob * (3 * Dm) + hh * HDn + g * 8;
        qreg[0] = *(const bf16x8*)qp;
        qreg[1] = *(const bf16x8*)(qp + 32);
    }

    f32x4 accO[4] = {};               // O[q=4g+r][d=16nf+l15]
    float mrun = -3.0e38f, lrun = 0.f;

    for (int kt = 0; kt < nkt; ++kt) {
        const int kb = kt * 64;
        __syncthreads();   // previous tile fully consumed
#pragma unroll
        for (int t2 = 0; t2 < 4; ++t2) {
            int c = tid + t2 * 128;
            int kr = c >> 3;
            int d8 = (c & 7) * 8;
            const bf16* gp = qkv + (size_t)(kb + kr) * (3 * Dm) + Dm + hh * HDn + d8;
            bf16x8 v = *(const bf16x8*)gp;
            *(bf16x8*)((char*)Ks + kr * 128 + ((d8 * 2) ^ ((kr & 7) << 4))) = v;
        }
#pragma unroll
        for (int t2 = 0; t2 < 4; ++t2) {
            int c = tid + t2 * 128;
            int k = c >> 3, d0 = (c & 7) * 8;
            const bf16* gp = qkv + (size_t)(kb + k) * (3 * Dm) + 2 * Dm + hh * HDn + d0;
            bf16x8 v = *(const bf16x8*)gp;
#pragma unroll
            for (int j = 0; j < 8; ++j) {
                int d = d0 + j;
                *(bf16*)((char*)Vt + d * 128 + ((2 * k) ^ ((d & 7) << 4))) = v[j];
            }
        }
        __syncthreads();

        // ---- S^T = K . Q^T ----
        f32x4 accS[4] = {};
        __builtin_amdgcn_s_setprio(1);
#pragma unroll
        for (int s2 = 0; s2 < 2; ++s2)
#pragma unroll
            for (int mf = 0; mf < 4; ++mf) {
                int kr = mf * 16 + l15;
                bf16x8 af = *(const bf16x8*)((char*)Ks + kr * 128 + ((s2 * 64 + g * 16) ^ ((kr & 7) << 4)));
                accS[mf] = __builtin_amdgcn_mfma_f32_16x16x32_bf16(af, qreg[s2], accS[mf], 0, 0, 0);
            }
        __builtin_amdgcn_s_setprio(0);

        // ---- online softmax (stats per q = l15) ----
        float p[16];
        float tmax = -3.0e38f;
#pragma unroll
        for (int mf = 0; mf < 4; ++mf)
#pragma unroll
            for (int r = 0; r < 4; ++r) {
                int k = kb + mf * 16 + g * 4 + r;
                float sv = accS[mf][r] * 0.125f + addb[k];
                if (k > qglob) sv = -3.0e38f;     // causal
                p[mf * 4 + r] = sv;
                tmax = fmaxf(tmax, sv);
            }
        tmax = fmaxf(tmax, __shfl_xor(tmax, 16, 64));
        tmax = fmaxf(tmax, __shfl_xor(tmax, 32, 64));
        float mnew = fmaxf(mrun, tmax);
        float alpha = expf(mrun - mnew);
        float psum = 0.f;
#pragma unroll
        for (int i = 0; i < 16; ++i) { float e = expf(p[i] - mnew); p[i] = e; psum += e; }
        psum += __shfl_xor(psum, 16, 64);
        psum += __shfl_xor(psum, 32, 64);
        lrun = lrun * alpha + psum;
        mrun = mnew;

        if (g == 0) bcast[wq][l15] = alpha;
        f32x4 av = *(f32x4*)&bcast[wq][g * 4];
#pragma unroll
        for (int nf = 0; nf < 4; ++nf)
#pragma unroll
            for (int r = 0; r < 4; ++r) accO[nf][r] *= av[r];

        // ---- P (bf16) -> per-wave LDS, re-read as PV A-fragments ----
        char* pw = (char*)Pw[wq];
#pragma unroll
        for (int mf = 0; mf < 4; ++mf) {
            bf16x4 pk;
            pk[0] = (bf16)p[mf * 4 + 0]; pk[1] = (bf16)p[mf * 4 + 1];
            pk[2] = (bf16)p[mf * 4 + 2]; pk[3] = (bf16)p[mf * 4 + 3];
            *(bf16x4*)(pw + l15 * 128 + ((32 * mf + 8 * g) ^ ((l15 & 7) << 4))) = pk;
        }
        bf16x8 pa[2];
#pragma unroll
        for (int s2 = 0; s2 < 2; ++s2)
            pa[s2] = *(const bf16x8*)(pw + l15 * 128 + ((s2 * 64 + g * 16) ^ ((l15 & 7) << 4)));

        // ---- O += P . V ----
        __builtin_amdgcn_s_setprio(1);
#pragma unroll
        for (int s2 = 0; s2 < 2; ++s2)
#pragma unroll
            for (int nf = 0; nf < 4; ++nf) {
                int d = nf * 16 + l15;
                bf16x8 bfg = *(const bf16x8*)((char*)Vt + d * 128 + ((s2 * 64 + g * 16) ^ ((d & 7) << 4)));
                accO[nf] = __builtin_amdgcn_mfma_f32_16x16x32_bf16(pa[s2], bfg, accO[nf], 0, 0, 0);
            }
        __builtin_amdgcn_s_setprio(0);
    }

    if (g == 0) bcast[wq][l15] = 1.0f / lrun;
    f32x4 lv = *(f32x4*)&bcast[wq][g * 4];
#pragma unroll
    for (int nf = 0; nf < 4; ++nf)
#pragma unroll
        for (int r = 0; r < 4; ++r) {
            int row = qt * 32 + wq * 16 + 4 * g + r;
            int col = hh * HDn + nf * 16 + l15;
            out[(size_t)row * Dm + col] = (bf16)(accO[nf][r] * lv[r]);
        }
}

// ---------------- launch ----------------
extern "C" void kernel_launch(void* const* d_in, const int* in_sizes, int n_in,
                              void* d_out, int out_size, void* d_ws, size_t ws_size,
                              hipStream_t stream) {
    const int*   x      = (const int*)d_in[0];
    const float* amask  = (const float*)d_in[1];
    const float* tok    = (const float*)d_in[2];
    const float* pos    = (const float*)d_in[3];
    const float* ln1_g  = (const float*)d_in[4];
    const float* ln1_b  = (const float*)d_in[5];
    const float* qkv_w  = (const float*)d_in[6];
    const float* qkv_b  = (const float*)d_in[7];
    const float* out_w  = (const float*)d_in[8];
    const float* out_b  = (const float*)d_in[9];
    const float* ln2_g  = (const float*)d_in[10];
    const float* ln2_b  = (const float*)d_in[11];
    const float* fc1_w  = (const float*)d_in[12];
    const float* fc1_b  = (const float*)d_in[13];
    const float* fc2_w  = (const float*)d_in[14];
    const float* fc2_b  = (const float*)d_in[15];
    const float* lnf_g  = (const float*)d_in[16];
    const float* lnf_b  = (const float*)d_in[17];
    const float* lm_w   = (const float*)d_in[18];

    char* ws = (char*)d_ws;
    float* h      = (float*)(ws + 0);                       // 4 MB
    bf16*  qkv_bf = (bf16*) (ws + (4u << 20));              // 6 MB
    bf16*  xn_bf  = (bf16*) (ws + (16u << 20));             // 2 MB
    bf16*  wv_bf  = (bf16*) (ws + (18u << 20));             // 2 MB
    bf16*  ff1_bf = (bf16*) (ws + (20u << 20));             // 8 MB
    bf16*  Wbuf   = (bf16*) (ws + (28u << 20));             // 24 MB (per-layer weights)
    bf16* qT  = Wbuf;
    bf16* oT  = qT  + 3145728;
    bf16* f1T = oT  + 1048576;
    bf16* f2T = f1T + 4194304;
    bf16* lm_bf = (bf16*)(ws + (52u << 20));                // 100 MB (if ws allows)
    float* outf = (float*)d_out;

    const bool big_ws = ws_size >= ((size_t)153 << 20);

    embed_k<<<Tn, 256, 0, stream>>>(x, tok, pos, h);

    for (int l = 0; l < Lnum; ++l) {
        const float* l1g = ln1_g + (size_t)l * Dm;
        const float* l1b = ln1_b + (size_t)l * Dm;
        const float* qw  = qkv_w + (size_t)l * Dm * 3 * Dm;
        const float* qb  = qkv_b + (size_t)l * 3 * Dm;
        const float* ow  = out_w + (size_t)l * Dm * Dm;
        const float* ob  = out_b + (size_t)l * Dm;
        const float* l2g = ln2_g + (size_t)l * Dm;
        const float* l2b = ln2_b + (size_t)l * Dm;
        const float* f1w = fc1_w + (size_t)l * Dm * 4 * Dm;
        const float* f1b = fc1_b + (size_t)l * 4 * Dm;
        const float* f2w = fc2_w + (size_t)l * 4 * Dm * Dm;
        const float* f2b = fc2_b + (size_t)l * Dm;

        // fused: per-layer weight convert (cache-warm) + LN1
        tconv_ln_k<<<4096, 256, 0, stream>>>(qw, ow, f1w, f2w, Wbuf, h, l1g, l1b, xn_bf);
        // qkv = xn @ qw + qb (bf16 out): 64x64 tiles, 768 blocks (3/CU)
        mgemm_k<64, 64, 0, false, true, 0, false><<<768, 256, 0, stream>>>(
            xn_bf, qT, qb, nullptr, qkv_bf, 3 * Dm, Dm, 16, 48);
        // flash attention: 512 blocks x 128 thr, LPT-balanced causal
        fattn_k<<<512, 128, 0, stream>>>(qkv_bf, amask, wv_bf);
        // h = h + wv @ ow + ob: 32x64 tiles, 512 blocks (2/CU)
        mgemm_k<32, 64, 0, true, false, 0, false><<<512, 256, 0, stream>>>(
            wv_bf, oT, ob, h, h, Dm, Dm, 32, 16);
        ln_k<<<Tn, 256, 0, stream>>>(h, l2g, l2b, xn_bf);
        // ff1 = gelu(xn @ f1w + f1b): 64x64 tiles, 1024 blocks (4/CU)
        mgemm_k<64, 64, 1, false, true, 0, false><<<1024, 256, 0, stream>>>(
            xn_bf, f1T, f1b, nullptr, ff1_bf, 4 * Dm, Dm, 16, 64);
        // h = h + ff1 @ f2w + f2b: 32x64 tiles, 512 blocks (2/CU)
        mgemm_k<32, 64, 0, true, false, 0, false><<<512, 256, 0, stream>>>(
            ff1_bf, f2T, f2b, h, h, Dm, 4 * Dm, 32, 16);
    }

    // logits = xn @ lm_w^T: 128x128 tiles, nbn padded 393 -> 400 (NTAIL)
    if (big_ws) {
        // fused final LN + lm_w convert (independent producers)
        lnf_cvt_k<<<3072, 256, 0, stream>>>(h, lnf_g, lnf_b, xn_bf, lm_w, lm_bf,
                                            (Vn * Dm) / 8);
        mgemm_k<128, 128, 0, false, false, 0, true><<<8 * 400, 256, 0, stream>>>(
            xn_bf, lm_bf, nullptr, nullptr, outf, Vn, Dm, 8, 400);
    } else {
        ln_k<<<Tn, 256, 0, stream>>>(h, lnf_g, lnf_b, xn_bf);
        mgemm_k<128, 128, 0, false, false, 1, true><<<8 * 400, 256, 0, stream>>>(
            xn_bf, lm_w, nullptr, nullptr, outf, Vn, Dm, 8, 400);
    }
}